// Round 1
// baseline (125.005 us; speedup 1.0000x reference)
//
#include <hip/hip_runtime.h>
#include <stdint.h>

typedef float  f32x4 __attribute__((ext_vector_type(4)));
typedef short  s16x8 __attribute__((ext_vector_type(8)));

constexpr int D       = 64;     // feature dim (fixed by problem)
constexpr int SPLITS  = 16;     // M-dimension chunks (grid.x)
constexpr int TILE_M  = 128;    // targets staged in LDS per tile

__device__ __forceinline__ unsigned short f2bf(float f) {
    // round-to-nearest-even fp32 -> bf16 (inputs are finite normals; no NaN path)
    unsigned int u = __float_as_uint(f);
    u = (u + 0x7FFFu + ((u >> 16) & 1u)) >> 16;
    return (unsigned short)u;
}

// ---- prep: one wave per target row: Y fp32 -> bf16, t[m] = ||y||^2 - psi[m]
__global__ void prep_targets(const float* __restrict__ Y,
                             const float* __restrict__ psi,
                             unsigned short* __restrict__ Yb,
                             float* __restrict__ t) {
    const int lane = threadIdx.x & 63;
    const int wave = threadIdx.x >> 6;
    const int row  = blockIdx.x * 4 + wave;
    const float v = Y[row * D + lane];
    Yb[row * D + lane] = f2bf(v);
    float s = v * v;
    #pragma unroll
    for (int off = 32; off >= 1; off >>= 1) s += __shfl_xor(s, off);
    if (lane == 0) t[row] = s - psi[row];
}

// ---- mean(psi), single block
__global__ void mean_psi_kernel(const float* __restrict__ psi,
                                float* __restrict__ meanp, int M) {
    __shared__ float red[256];
    float s = 0.f;
    for (int i = threadIdx.x; i < M; i += 256) s += psi[i];
    red[threadIdx.x] = s;
    __syncthreads();
    for (int w = 128; w > 0; w >>= 1) {
        if (threadIdx.x < w) red[threadIdx.x] += red[threadIdx.x + w];
        __syncthreads();
    }
    if (threadIdx.x == 0) meanp[0] = red[0] / (float)M;
}

// ---- main: fused bf16-MFMA dot + running-min epilogue
// grid = (SPLITS, N/128); block = 256 (4 waves). Each block: 128 source rows,
// one M-chunk of M/SPLITS targets, staged through LDS in TILE_M tiles.
// LDS layout XOR-swizzled in 16B granules: logical chunk c of row r stored at
// c ^ (r & 7)  -> ds_read_b128 B-frag reads have <=2-way bank aliasing (free).
__global__ __launch_bounds__(256, 4)
void sdot_main(const float* __restrict__ X,
               const unsigned short* __restrict__ Yb,
               const float* __restrict__ t,
               float* __restrict__ partial,
               int M) {
    __shared__ unsigned short ly[TILE_M * 64];
    __shared__ float lt[TILE_M];

    const int tid  = threadIdx.x;
    const int wave = tid >> 6;
    const int lane = tid & 63;
    const int quad = lane >> 4;
    const int r16  = lane & 15;
    const int chunk  = blockIdx.x;
    const int rowgrp = blockIdx.y;
    const int CH      = M / SPLITS;
    const int m_begin = chunk * CH;

    // A fragments: 2 source groups (g) x 2 K-halves (h); A[m=lane&15][k=quad*8+j]
    s16x8 a[2][2];
    #pragma unroll
    for (int g = 0; g < 2; g++) {
        const int srow = rowgrp * 128 + g * 64 + wave * 16 + r16;
        #pragma unroll
        for (int h = 0; h < 2; h++) {
            const float4 u0 = *reinterpret_cast<const float4*>(X + srow * D + h * 32 + quad * 8);
            const float4 u1 = *reinterpret_cast<const float4*>(X + srow * D + h * 32 + quad * 8 + 4);
            s16x8 fr;
            fr[0] = (short)f2bf(u0.x); fr[1] = (short)f2bf(u0.y);
            fr[2] = (short)f2bf(u0.z); fr[3] = (short)f2bf(u0.w);
            fr[4] = (short)f2bf(u1.x); fr[5] = (short)f2bf(u1.y);
            fr[6] = (short)f2bf(u1.z); fr[7] = (short)f2bf(u1.w);
            a[g][h] = fr;
        }
    }

    float rmin[2][4];
    #pragma unroll
    for (int g = 0; g < 2; g++)
        #pragma unroll
        for (int r = 0; r < 4; r++) rmin[g][r] = 1e30f;

    for (int mb = m_begin; mb < m_begin + CH; mb += TILE_M) {
        __syncthreads();
        // stage TILE_M x 64 bf16 (16 KB) : 4 iters x 256 thr x 16 B
        #pragma unroll
        for (int i = 0; i < 4; i++) {
            const int idx = i * 256 + tid;        // granule index (8 ushorts each)
            const int row = idx >> 3;
            const int c   = idx & 7;
            const int cp  = c ^ (row & 7);
            const uint4 v = *reinterpret_cast<const uint4*>(Yb + (size_t)(mb + row) * D + c * 8);
            *reinterpret_cast<uint4*>(&ly[row * 64 + cp * 8]) = v;
        }
        if (tid < TILE_M) lt[tid] = t[mb + tid];
        __syncthreads();

        #pragma unroll
        for (int st = 0; st < TILE_M / 16; st++) {
            const int trow = st * 16 + r16;       // B[n=lane&15][k=quad*8+j]
            const int sw   = trow & 7;
            const s16x8 b0 = *reinterpret_cast<const s16x8*>(&ly[trow * 64 + ((quad    ) ^ sw) * 8]);
            const s16x8 b1 = *reinterpret_cast<const s16x8*>(&ly[trow * 64 + ((quad + 4) ^ sw) * 8]);
            const float tv = lt[trow];
            #pragma unroll
            for (int g = 0; g < 2; g++) {
                f32x4 acc = {0.f, 0.f, 0.f, 0.f};
                acc = __builtin_amdgcn_mfma_f32_16x16x32_bf16(a[g][0], b0, acc, 0, 0, 0);
                acc = __builtin_amdgcn_mfma_f32_16x16x32_bf16(a[g][1], b1, acc, 0, 0, 0);
                #pragma unroll
                for (int r = 0; r < 4; r++) {
                    const float c = tv - 2.0f * acc[r];   // ||y||^2 - psi - 2<x,y>
                    rmin[g][r] = fminf(rmin[g][r], c);
                }
            }
        }
    }

    // min across the 16 lanes (cols) of each quad
    #pragma unroll
    for (int off = 1; off <= 8; off <<= 1)
        #pragma unroll
        for (int g = 0; g < 2; g++)
            #pragma unroll
            for (int r = 0; r < 4; r++)
                rmin[g][r] = fminf(rmin[g][r], __shfl_xor(rmin[g][r], off));

    if (r16 == 0) {
        #pragma unroll
        for (int g = 0; g < 2; g++) {
            const int rowbase = rowgrp * 128 + g * 64 + wave * 16 + quad * 4;
            #pragma unroll
            for (int r = 0; r < 4; r++)
                partial[(size_t)(rowbase + r) * SPLITS + chunk] = rmin[g][r];
        }
    }
}

// ---- finalize: out[n] = ||x_n||^2 + mean(psi) + min over SPLITS partials
__global__ void finalize(const float* __restrict__ X,
                         const float* __restrict__ partial,
                         const float* __restrict__ meanp,
                         float* __restrict__ out) {
    const int lane = threadIdx.x & 63;
    const int wave = threadIdx.x >> 6;
    const int row  = blockIdx.x * 4 + wave;
    const float x = X[row * D + lane];
    float s = x * x;
    #pragma unroll
    for (int off = 32; off >= 1; off >>= 1) s += __shfl_xor(s, off);
    float pm = (lane < SPLITS) ? partial[(size_t)row * SPLITS + lane] : 1e30f;
    #pragma unroll
    for (int off = 32; off >= 1; off >>= 1) pm = fminf(pm, __shfl_xor(pm, off));
    if (lane == 0) out[row] = s + meanp[0] + pm;
}

extern "C" void kernel_launch(void* const* d_in, const int* in_sizes, int n_in,
                              void* d_out, int out_size, void* d_ws, size_t ws_size,
                              hipStream_t stream) {
    const float* X   = (const float*)d_in[0];   // [N, 64]
    const float* Y   = (const float*)d_in[1];   // [M, 64]
    const float* psi = (const float*)d_in[2];   // [M]
    float* out = (float*)d_out;

    const int N = in_sizes[0] / D;   // 8192
    const int M = in_sizes[2];       // 32768

    char* ws = (char*)d_ws;
    unsigned short* Yb = (unsigned short*)ws;                 // M*64 bf16  (4 MB)
    size_t off = (size_t)M * D * sizeof(unsigned short);
    float* t = (float*)(ws + off);                            // M floats   (128 KB)
    off += (size_t)M * sizeof(float);
    float* partial = (float*)(ws + off);                      // N*SPLITS   (512 KB)
    off += (size_t)N * SPLITS * sizeof(float);
    float* meanp = (float*)(ws + off);                        // 1 float

    prep_targets<<<M / 4, 256, 0, stream>>>(Y, psi, Yb, t);
    mean_psi_kernel<<<1, 256, 0, stream>>>(psi, meanp, M);
    dim3 grid(SPLITS, N / 128);
    sdot_main<<<grid, 256, 0, stream>>>(X, Yb, t, partial, M);
    finalize<<<N / 4, 256, 0, stream>>>(X, partial, meanp, out);
}